// Round 1
// baseline (1634.400 us; speedup 1.0000x reference)
//
#include <hip/hip_runtime.h>
#include <cstdint>

#define Bq 2
#define Tq 2048
#define Dq 1024
#define Hq 16
#define Kq 64
#define FFNq 4096
#define NCHUNK 32
#define ROWS (Bq*Tq)   // 4096
#define STW 4160       // 64*65 state/tile words

enum { ACT_NONE = 0, ACT_ELU1 = 1, ACT_GELU = 2 };

// ---------------- LayerNorm (one block per row, D=1024) ----------------
__global__ __launch_bounds__(256) void ln_kernel(
    const float* __restrict__ x, const float* __restrict__ w,
    const float* __restrict__ b, float* __restrict__ out)
{
  const int row = blockIdx.x;
  const int tid = threadIdx.x;
  const float* xr = x + (size_t)row * Dq;
  float4 v = *(const float4*)(xr + tid * 4);
  float s  = v.x + v.y + v.z + v.w;
  float s2 = v.x*v.x + v.y*v.y + v.z*v.z + v.w*v.w;
  #pragma unroll
  for (int off = 32; off > 0; off >>= 1) {
    s  += __shfl_down(s,  off);
    s2 += __shfl_down(s2, off);
  }
  __shared__ float rs[4], rs2[4];
  const int wid = tid >> 6, lane = tid & 63;
  if (lane == 0) { rs[wid] = s; rs2[wid] = s2; }
  __syncthreads();
  const float ts  = rs[0] + rs[1] + rs[2] + rs[3];
  const float ts2 = rs2[0] + rs2[1] + rs2[2] + rs2[3];
  const float mean = ts * (1.f / Dq);
  const float var  = ts2 * (1.f / Dq) - mean * mean;
  const float rstd = rsqrtf(var + 1e-5f);
  const float4 wv = *(const float4*)(w + tid * 4);
  const float4 bv = *(const float4*)(b + tid * 4);
  float4 o;
  o.x = (v.x - mean) * rstd * wv.x + bv.x;
  o.y = (v.y - mean) * rstd * wv.y + bv.y;
  o.z = (v.z - mean) * rstd * wv.z + bv.z;
  o.w = (v.w - mean) * rstd * wv.w + bv.w;
  *(float4*)(out + (size_t)row * Dq + tid * 4) = o;
}

// ---------------- fp32 SIMT GEMM: C = act(A@W + bias) (+res) ----------------
// A[M,Kd] row-major, W[Kd,N] row-major. 128x128 tile, BK=16, 256 thr, 8x8/thr.
template<int ACT, bool RES>
__global__ __launch_bounds__(256) void gemm_kernel(
    const float* __restrict__ A, const float* __restrict__ W,
    const float* __restrict__ bias, const float* __restrict__ res,
    float* __restrict__ C, int M, int N, int Kd)
{
  __shared__ float As[16][128];
  __shared__ float Bs[16][128];
  const int tid = threadIdx.x;
  const int tx = tid & 15, ty = tid >> 4;
  const int rowBase = blockIdx.y * 128;
  const int colBase = blockIdx.x * 128;
  float acc[2][2][4][4] = {};
  for (int k0 = 0; k0 < Kd; k0 += 16) {
    #pragma unroll
    for (int l = 0; l < 2; ++l) {
      const int s = tid + l * 256;            // 0..511
      const int ar = s >> 2, ak = (s & 3) << 2;
      const float4 av = *(const float4*)(A + (size_t)(rowBase + ar) * Kd + k0 + ak);
      As[ak + 0][ar] = av.x; As[ak + 1][ar] = av.y;
      As[ak + 2][ar] = av.z; As[ak + 3][ar] = av.w;
      const int bk = s >> 5, bc = (s & 31) << 2;
      *(float4*)(&Bs[bk][bc]) = *(const float4*)(W + (size_t)(k0 + bk) * N + colBase + bc);
    }
    __syncthreads();
    #pragma unroll
    for (int kk = 0; kk < 16; ++kk) {
      float a[2][4], bb[2][4];
      *(float4*)a[0]  = *(const float4*)(&As[kk][ty * 4]);
      *(float4*)a[1]  = *(const float4*)(&As[kk][ty * 4 + 64]);
      *(float4*)bb[0] = *(const float4*)(&Bs[kk][tx * 4]);
      *(float4*)bb[1] = *(const float4*)(&Bs[kk][tx * 4 + 64]);
      #pragma unroll
      for (int hi = 0; hi < 2; ++hi)
        #pragma unroll
        for (int hj = 0; hj < 2; ++hj)
          #pragma unroll
          for (int i = 0; i < 4; ++i)
            #pragma unroll
            for (int j = 0; j < 4; ++j)
              acc[hi][hj][i][j] += a[hi][i] * bb[hj][j];
    }
    __syncthreads();
  }
  #pragma unroll
  for (int hi = 0; hi < 2; ++hi)
    #pragma unroll
    for (int i = 0; i < 4; ++i) {
      const int row = rowBase + hi * 64 + ty * 4 + i;
      #pragma unroll
      for (int hj = 0; hj < 2; ++hj) {
        const int col = colBase + hj * 64 + tx * 4;
        float4 o;
        float* op = &o.x;
        #pragma unroll
        for (int j = 0; j < 4; ++j) {
          float val = acc[hi][hj][i][j] + bias[col + j];
          if (ACT == ACT_ELU1)      val = (val >= 0.f) ? (val + 1.f) : expf(val);
          else if (ACT == ACT_GELU) val = 0.5f * val * (1.f + erff(val * 0.70710678118f));
          if (RES) val += res[(size_t)row * N + col + j];
          op[j] = val;
        }
        *(float4*)(C + (size_t)row * N + col) = o;
      }
    }
}

// ---------------- decay head: llam[row][h] = log(max(sigmoid(xn@dec_w+b),1e-8)) ----------------
__global__ __launch_bounds__(256) void declam_kernel(
    const float* __restrict__ xn, const float* __restrict__ dec_w,
    const float* __restrict__ dec_b, float* __restrict__ llam)
{
  const int row = blockIdx.x;
  const int tid = threadIdx.x;
  const int h = tid & 15, part = tid >> 4;
  const float* xr = xn + (size_t)row * Dq;
  float s = 0.f;
  #pragma unroll 4
  for (int i = 0; i < 64; ++i) {
    const int d = part * 64 + i;
    s += xr[d] * dec_w[d * Hq + h];
  }
  __shared__ float ps[256];
  ps[tid] = s;
  __syncthreads();
  if (tid < 16) {
    float t = dec_b[tid];
    #pragma unroll
    for (int p = 0; p < 16; ++p) t += ps[p * 16 + tid];
    float lam = 1.f / (1.f + expf(-t));
    lam = fmaxf(lam, 1e-8f);
    llam[(size_t)row * Hq + tid] = logf(lam);
  }
}

// ---------------- LION phase A: per-chunk intra output + state deltas ----------------
// grid (chunk=32, bh=32), 256 threads.
__global__ __launch_bounds__(256) void lion_chunk_kernel(
    const float* __restrict__ qb, const float* __restrict__ kb,
    const float* __restrict__ vb, const float* __restrict__ llam,
    float* __restrict__ intra, float* __restrict__ dS,
    float* __restrict__ dR, float* __restrict__ lwout)
{
  const int c  = blockIdx.x;
  const int bh = blockIdx.y;
  const int b = bh >> 4, h = bh & 15;
  const int tid = threadIdx.x;
  const int tx = tid & 15, ty = tid >> 4;

  __shared__ float qs[64 * 65];   // later aliased as the A-coeff matrix
  __shared__ float ks[64 * 65];
  __shared__ float vs[64 * 65];
  __shared__ float lw[64];
  __shared__ float e1[64], e2[64];

  const size_t rowbase = ((size_t)(b * Tq + c * 64)) * Dq + h * 64;
  #pragma unroll
  for (int r = 0; r < 4; ++r) {
    const int s = tid + r * 256;              // 0..1023
    const int u = s >> 4, f4 = (s & 15) << 2;
    const float4 qv = *(const float4*)(qb + rowbase + (size_t)u * Dq + f4);
    const float4 kv = *(const float4*)(kb + rowbase + (size_t)u * Dq + f4);
    const float4 vv = *(const float4*)(vb + rowbase + (size_t)u * Dq + f4);
    const int o = u * 65 + f4;
    qs[o+0]=qv.x; qs[o+1]=qv.y; qs[o+2]=qv.z; qs[o+3]=qv.w;
    ks[o+0]=kv.x; ks[o+1]=kv.y; ks[o+2]=kv.z; ks[o+3]=kv.w;
    vs[o+0]=vv.x; vs[o+1]=vv.y; vs[o+2]=vv.z; vs[o+3]=vv.w;
  }
  if (tid < 64) {   // wave 0: inclusive scan of log-lambda over the chunk
    const float lg = llam[((size_t)(b * Tq + c * 64 + tid)) * Hq + h];
    float sum = lg;
    #pragma unroll
    for (int off = 1; off < 64; off <<= 1) {
      const float y = __shfl_up(sum, off);
      if (tid >= off) sum += y;
    }
    lw[tid] = sum;
    const float lwE = __shfl(sum, 63);
    e1[tid] = expf(lwE - sum);   // decay from t to chunk end
    e2[tid] = expf(sum);         // decay from chunk start through t
    lwout[((size_t)bh * NCHUNK + c) * 64 + tid] = sum;
  }
  __syncthreads();

  // ---- A = (Q Kᵀ) ∘ exp(-|lw_i - lw_j|)  (covers fwd j<=i and bwd j>i, diag once)
  float am[4][4] = {};
  for (int kk = 0; kk < 64; ++kk) {
    float a[4], bv_[4];
    #pragma unroll
    for (int i = 0; i < 4; ++i) a[i]  = qs[(ty * 4 + i) * 65 + kk];
    #pragma unroll
    for (int j = 0; j < 4; ++j) bv_[j] = ks[(tx * 4 + j) * 65 + kk];
    #pragma unroll
    for (int i = 0; i < 4; ++i)
      #pragma unroll
      for (int j = 0; j < 4; ++j)
        am[i][j] += a[i] * bv_[j];
  }
  __syncthreads();                 // all reads of qs done
  float* Am = qs;                  // alias
  #pragma unroll
  for (int i = 0; i < 4; ++i) {
    const float lwi = lw[ty * 4 + i];
    #pragma unroll
    for (int j = 0; j < 4; ++j)
      Am[(ty * 4 + i) * 65 + tx * 4 + j] = am[i][j] * expf(-fabsf(lwi - lw[tx * 4 + j]));
  }
  __syncthreads();

  const size_t obase = ((size_t)bh * NCHUNK + c) * STW;

  // ---- intra = A @ V_ext (col 64 = row-sum of A, since v_ext last col = 1)
  {
    float acc2[4][4] = {};
    for (int uj = 0; uj < 64; ++uj) {
      float a[4], bv_[4];
      #pragma unroll
      for (int i = 0; i < 4; ++i) a[i]  = Am[(ty * 4 + i) * 65 + uj];
      #pragma unroll
      for (int j = 0; j < 4; ++j) bv_[j] = vs[uj * 65 + tx * 4 + j];
      #pragma unroll
      for (int i = 0; i < 4; ++i)
        #pragma unroll
        for (int j = 0; j < 4; ++j)
          acc2[i][j] += a[i] * bv_[j];
    }
    #pragma unroll
    for (int i = 0; i < 4; ++i)
      #pragma unroll
      for (int j = 0; j < 4; ++j)
        intra[obase + (ty * 4 + i) * 65 + tx * 4 + j] = acc2[i][j];
  }
  if (tid < 64) {
    float s = 0.f;
    for (int uj = 0; uj < 64; ++uj) s += Am[tid * 65 + uj];
    intra[obase + tid * 65 + 64] = s;
  }

  // ---- dS[k][kv] = Σ_u e1[u]·k_u[k]·v_u[kv] ;  dR with e2
  {
    float accS[4][4] = {}, accR[4][4] = {};
    for (int u = 0; u < 64; ++u) {
      const float w1 = e1[u], w2 = e2[u];
      float kr[4], vr[4];
      #pragma unroll
      for (int i = 0; i < 4; ++i) kr[i] = ks[u * 65 + ty * 4 + i];
      #pragma unroll
      for (int j = 0; j < 4; ++j) vr[j] = vs[u * 65 + tx * 4 + j];
      #pragma unroll
      for (int i = 0; i < 4; ++i)
        #pragma unroll
        for (int j = 0; j < 4; ++j) {
          const float p = kr[i] * vr[j];
          accS[i][j] += w1 * p;
          accR[i][j] += w2 * p;
        }
    }
    #pragma unroll
    for (int i = 0; i < 4; ++i)
      #pragma unroll
      for (int j = 0; j < 4; ++j) {
        const size_t idx = obase + (ty * 4 + i) * 65 + tx * 4 + j;
        dS[idx] = accS[i][j];
        dR[idx] = accR[i][j];
      }
  }
  if (tid < 64) {
    float sS = 0.f, sR = 0.f;
    for (int u = 0; u < 64; ++u) {
      const float kv_ = ks[u * 65 + tid];
      sS += e1[u] * kv_;
      sR += e2[u] * kv_;
    }
    dS[obase + tid * 65 + 64] = sS;
    dR[obase + tid * 65 + 64] = sR;
  }
}

// ---------------- LION phase B: sequential chunk-state combine (in-place) ----------------
// grid 64: (bh, dir). Writes state-BEFORE-chunk into the delta slot.
__global__ __launch_bounds__(256) void lion_state_kernel(
    float* __restrict__ dS, float* __restrict__ dR,
    const float* __restrict__ lwbuf)
{
  const int bh  = blockIdx.x >> 1;
  const int dir = blockIdx.x & 1;
  const int tid = threadIdx.x;
  float st[17];
  #pragma unroll
  for (int r = 0; r < 17; ++r) st[r] = 0.f;
  if (dir == 0) {
    for (int c = 0; c < NCHUNK; ++c) {
      const float d = expf(lwbuf[((size_t)bh * NCHUNK + c) * 64 + 63]);
      const size_t base = ((size_t)bh * NCHUNK + c) * STW;
      #pragma unroll
      for (int r = 0; r < 17; ++r) {
        const int e = tid + r * 256;
        if (e < STW) {
          const float tmp = dS[base + e];
          dS[base + e] = st[r];
          st[r] = fmaf(d, st[r], tmp);
        }
      }
    }
  } else {
    for (int c = NCHUNK - 1; c >= 0; --c) {
      const float d = expf(lwbuf[((size_t)bh * NCHUNK + c) * 64 + 63]);
      const size_t base = ((size_t)bh * NCHUNK + c) * STW;
      #pragma unroll
      for (int r = 0; r < 17; ++r) {
        const int e = tid + r * 256;
        if (e < STW) {
          const float tmp = dR[base + e];
          dR[base + e] = st[r];
          st[r] = fmaf(d, st[r], tmp);
        }
      }
    }
  }
}

// ---------------- LION phase C: cross-chunk terms + normalize -> attn ----------------
__global__ __launch_bounds__(256) void lion_cross_kernel(
    const float* __restrict__ qb, const float* __restrict__ intra,
    const float* __restrict__ Sst, const float* __restrict__ Rst,
    const float* __restrict__ lwbuf, float* __restrict__ attn)
{
  const int c  = blockIdx.x;
  const int bh = blockIdx.y;
  const int b = bh >> 4, h = bh & 15;
  const int tid = threadIdx.x;
  const int tx = tid & 15, ty = tid >> 4;

  __shared__ float qs[64 * 65];    // later aliased as out tile
  __shared__ float Ss[STW];
  __shared__ float Rs[STW];
  __shared__ float lw[64];

  const size_t rowbase = ((size_t)(b * Tq + c * 64)) * Dq + h * 64;
  #pragma unroll
  for (int r = 0; r < 4; ++r) {
    const int s = tid + r * 256;
    const int u = s >> 4, f4 = (s & 15) << 2;
    const float4 qv = *(const float4*)(qb + rowbase + (size_t)u * Dq + f4);
    const int o = u * 65 + f4;
    qs[o+0]=qv.x; qs[o+1]=qv.y; qs[o+2]=qv.z; qs[o+3]=qv.w;
  }
  const size_t obase = ((size_t)bh * NCHUNK + c) * STW;
  for (int e = tid; e < STW; e += 256) {
    Ss[e] = Sst[obase + e];
    Rs[e] = Rst[obase + e];
  }
  if (tid < 64) lw[tid] = lwbuf[((size_t)bh * NCHUNK + c) * 64 + tid];
  __syncthreads();
  const float lwE = lw[63];

  // cross = exp(lw_i)·(q_i·S_c) + exp(lwE-lw_i)·(q_i·R_c)
  float aS[4][4] = {}, aR[4][4] = {};
  for (int kk = 0; kk < 64; ++kk) {
    float a[4], s4[4], r4[4];
    #pragma unroll
    for (int i = 0; i < 4; ++i) a[i]  = qs[(ty * 4 + i) * 65 + kk];
    #pragma unroll
    for (int j = 0; j < 4; ++j) { s4[j] = Ss[kk * 65 + tx * 4 + j]; r4[j] = Rs[kk * 65 + tx * 4 + j]; }
    #pragma unroll
    for (int i = 0; i < 4; ++i)
      #pragma unroll
      for (int j = 0; j < 4; ++j) {
        aS[i][j] += a[i] * s4[j];
        aR[i][j] += a[i] * r4[j];
      }
  }
  float dnS = 0.f, dnR = 0.f;
  if (tid < 64) {
    for (int kk = 0; kk < 64; ++kk) {
      const float qv = qs[tid * 65 + kk];
      dnS += qv * Ss[kk * 65 + 64];
      dnR += qv * Rs[kk * 65 + 64];
    }
  }
  __syncthreads();               // all reads of qs done
  float* outb = qs;              // alias
  #pragma unroll
  for (int i = 0; i < 4; ++i) {
    const float ef = expf(lw[ty * 4 + i]);
    const float eb = expf(lwE - lw[ty * 4 + i]);
    #pragma unroll
    for (int j = 0; j < 4; ++j) {
      const int idx = (ty * 4 + i) * 65 + tx * 4 + j;
      outb[idx] = intra[obase + idx] + ef * aS[i][j] + eb * aR[i][j];
    }
  }
  if (tid < 64) {
    outb[tid * 65 + 64] = intra[obase + tid * 65 + 64]
                        + expf(lw[tid]) * dnS + expf(lwE - lw[tid]) * dnR;
  }
  __syncthreads();
  for (int e = tid; e < 4096; e += 256) {
    const int ui = e >> 6, kk = e & 63;
    const float den = fmaxf(outb[ui * 65 + 64], 1e-6f);
    attn[rowbase + (size_t)ui * Dq + kk] = outb[ui * 65 + kk] / den;
  }
}

// ---------------- launch ----------------
extern "C" void kernel_launch(void* const* d_in, const int* in_sizes, int n_in,
                              void* d_out, int out_size, void* d_ws, size_t ws_size,
                              hipStream_t stream)
{
  const float* x     = (const float*)d_in[0];
  const float* q_w   = (const float*)d_in[1];
  const float* q_b   = (const float*)d_in[2];
  const float* k_w   = (const float*)d_in[3];
  const float* k_b   = (const float*)d_in[4];
  const float* v_w   = (const float*)d_in[5];
  const float* v_b   = (const float*)d_in[6];
  const float* o_w   = (const float*)d_in[7];
  const float* o_b   = (const float*)d_in[8];
  const float* ln1_w = (const float*)d_in[9];
  const float* ln1_b = (const float*)d_in[10];
  const float* ln2_w = (const float*)d_in[11];
  const float* ln2_b = (const float*)d_in[12];
  const float* dec_w = (const float*)d_in[13];
  const float* dec_b = (const float*)d_in[14];
  const float* f1_w  = (const float*)d_in[15];
  const float* f1_b  = (const float*)d_in[16];
  const float* f2_w  = (const float*)d_in[17];
  const float* f2_b  = (const float*)d_in[18];
  float* out = (float*)d_out;
  float* ws  = (float*)d_ws;

  size_t o = 0;
  float* xn     = ws + o; o += (size_t)ROWS * Dq;            // 4096x1024 (reused for LN2 out)
  float* attnb  = ws + o; o += (size_t)ROWS * Dq;
  float* xa     = ws + o; o += (size_t)ROWS * Dq;
  float* llam   = ws + o; o += (size_t)ROWS * Hq;
  float* lwb    = ws + o; o += (size_t)32 * NCHUNK * 64;
  float* dSb    = ws + o; o += (size_t)32 * NCHUNK * STW;
  float* dRb    = ws + o; o += (size_t)32 * NCHUNK * STW;
  float* qbuf   = ws + o; o += (size_t)ROWS * Dq;
  float* kbuf   = ws + o; o += (size_t)ROWS * Dq;
  float* vbuf   = ws + o; o += (size_t)ROWS * Dq;
  float* intrab = ws + o; o += (size_t)32 * NCHUNK * STW;
  float* hb = qbuf;   // FFN hidden (16.78M floats) aliases q/k/v/intra (16.84M), dead by then

  ln_kernel<<<ROWS, 256, 0, stream>>>(x, ln1_w, ln1_b, xn);
  gemm_kernel<ACT_ELU1, false><<<dim3(8, 32), 256, 0, stream>>>(xn, q_w, q_b, nullptr, qbuf, ROWS, Dq, Dq);
  gemm_kernel<ACT_ELU1, false><<<dim3(8, 32), 256, 0, stream>>>(xn, k_w, k_b, nullptr, kbuf, ROWS, Dq, Dq);
  gemm_kernel<ACT_NONE, false><<<dim3(8, 32), 256, 0, stream>>>(xn, v_w, v_b, nullptr, vbuf, ROWS, Dq, Dq);
  declam_kernel<<<ROWS, 256, 0, stream>>>(xn, dec_w, dec_b, llam);

  lion_chunk_kernel<<<dim3(NCHUNK, 32), 256, 0, stream>>>(qbuf, kbuf, vbuf, llam, intrab, dSb, dRb, lwb);
  lion_state_kernel<<<64, 256, 0, stream>>>(dSb, dRb, lwb);
  lion_cross_kernel<<<dim3(NCHUNK, 32), 256, 0, stream>>>(qbuf, intrab, dSb, dRb, lwb, attnb);

  gemm_kernel<ACT_NONE, true><<<dim3(8, 32), 256, 0, stream>>>(attnb, o_w, o_b, x, xa, ROWS, Dq, Dq);
  ln_kernel<<<ROWS, 256, 0, stream>>>(xa, ln2_w, ln2_b, xn);
  gemm_kernel<ACT_GELU, false><<<dim3(32, 32), 256, 0, stream>>>(xn, f1_w, f1_b, nullptr, hb, ROWS, FFNq, Dq);
  gemm_kernel<ACT_NONE, true><<<dim3(8, 32), 256, 0, stream>>>(hb, f2_w, f2_b, xa, out, ROWS, Dq, FFNq);
}

// Round 2
// 438.382 us; speedup vs baseline: 3.7283x; 3.7283x over previous
//
#include <hip/hip_runtime.h>
#include <cstdint>

#define Bq 2
#define Tq 2048
#define Dq 1024
#define Hq 16
#define Kq 64
#define FFNq 4096
#define NCHUNK 32
#define ROWS (Bq*Tq)   // 4096
#define STW 4160       // 64*65 state/tile words

typedef unsigned short u16;
typedef __attribute__((ext_vector_type(4))) float f32x4;

enum { ACT_NONE = 0, ACT_ELU1 = 1, ACT_GELU = 2 };

__device__ __forceinline__ u16 f2bf(float f) {
  uint32_t u = __float_as_uint(f);
  uint32_t r = (u + 0x7FFFu + ((u >> 16) & 1u)) >> 16;
  return (u16)r;
}
__device__ __forceinline__ float bf2f(u16 u) {
  return __uint_as_float(((uint32_t)u) << 16);
}
__device__ __forceinline__ float bflo(uint32_t w) { return __uint_as_float(w << 16); }
__device__ __forceinline__ float bfhi(uint32_t w) { return __uint_as_float(w & 0xffff0000u); }

__device__ __forceinline__ void gload16(const void* g, void* l) {
  __builtin_amdgcn_global_load_lds(
      (const __attribute__((address_space(1))) uint32_t*)g,
      (__attribute__((address_space(3))) uint32_t*)l, 16, 0, 0);
}

// ---------------- weight convert + transpose: src fp32 [Kd][N] -> dst bf16 [N][Kd] ----------------
__global__ __launch_bounds__(256) void wconv(const float* __restrict__ src,
                                             u16* __restrict__ dst, int Kd, int N)
{
  __shared__ float t[64][65];
  const int n0 = blockIdx.x * 64, k0 = blockIdx.y * 64;
  const int tid = threadIdx.x;
  #pragma unroll
  for (int r = 0; r < 4; ++r) {
    const int s = tid + r * 256;           // 0..1023
    const int kk = s >> 4, nn = (s & 15) << 2;
    const float4 v = *(const float4*)(src + (size_t)(k0 + kk) * N + n0 + nn);
    t[kk][nn] = v.x; t[kk][nn+1] = v.y; t[kk][nn+2] = v.z; t[kk][nn+3] = v.w;
  }
  __syncthreads();
  const int n = tid >> 2;
  const int ks = (tid & 3) << 4;
  uint32_t pk[8];
  #pragma unroll
  for (int j = 0; j < 8; ++j) {
    const float a = t[ks + 2*j][n];
    const float c = t[ks + 2*j + 1][n];
    pk[j] = (uint32_t)f2bf(a) | ((uint32_t)f2bf(c) << 16);
  }
  u16* drow = dst + (size_t)(n0 + n) * Kd + k0 + ks;
  *(uint4*)(drow)     = make_uint4(pk[0], pk[1], pk[2], pk[3]);
  *(uint4*)(drow + 8) = make_uint4(pk[4], pk[5], pk[6], pk[7]);
}

// ---------------- LayerNorm: fp32 in, bf16 out (+ optional fp32 out) ----------------
template<bool F32OUT>
__global__ __launch_bounds__(256) void ln_kernel(
    const float* __restrict__ x, const float* __restrict__ w,
    const float* __restrict__ b, float* __restrict__ outf, u16* __restrict__ outb)
{
  const int row = blockIdx.x;
  const int tid = threadIdx.x;
  const float* xr = x + (size_t)row * Dq;
  float4 v = *(const float4*)(xr + tid * 4);
  float s  = v.x + v.y + v.z + v.w;
  float s2 = v.x*v.x + v.y*v.y + v.z*v.z + v.w*v.w;
  #pragma unroll
  for (int off = 32; off > 0; off >>= 1) {
    s  += __shfl_down(s,  off);
    s2 += __shfl_down(s2, off);
  }
  __shared__ float rs[4], rs2[4];
  const int wid = tid >> 6, lane = tid & 63;
  if (lane == 0) { rs[wid] = s; rs2[wid] = s2; }
  __syncthreads();
  const float ts  = rs[0] + rs[1] + rs[2] + rs[3];
  const float ts2 = rs2[0] + rs2[1] + rs2[2] + rs2[3];
  const float mean = ts * (1.f / Dq);
  const float var  = ts2 * (1.f / Dq) - mean * mean;
  const float rstd = rsqrtf(var + 1e-5f);
  const float4 wv = *(const float4*)(w + tid * 4);
  const float4 bv = *(const float4*)(b + tid * 4);
  float4 o;
  o.x = (v.x - mean) * rstd * wv.x + bv.x;
  o.y = (v.y - mean) * rstd * wv.y + bv.y;
  o.z = (v.z - mean) * rstd * wv.z + bv.z;
  o.w = (v.w - mean) * rstd * wv.w + bv.w;
  if (F32OUT) *(float4*)(outf + (size_t)row * Dq + tid * 4) = o;
  uint2 p;
  p.x = (uint32_t)f2bf(o.x) | ((uint32_t)f2bf(o.y) << 16);
  p.y = (uint32_t)f2bf(o.z) | ((uint32_t)f2bf(o.w) << 16);
  *(uint2*)(outb + (size_t)row * Dq + tid * 4) = p;
}

// ---------------- bf16 MFMA GEMM: C = act(A @ BT^T + bias) (+res) ----------------
// A [M][Kd] bf16, BT [N][Kd] bf16. 128x128 tile, BK=32, 256 thr (4 waves, 2x2),
// each wave 64x64 = 4x4 frags of 16x16x32. m97 structure: global_load_lds + 2 barriers.
template<int ACT, bool RES, bool F32OUT>
__global__ __launch_bounds__(256) void mgemm(
    const u16* __restrict__ A, const u16* __restrict__ BT,
    const float* __restrict__ bias, const float* __restrict__ res,
    void* __restrict__ Cout, int M, int N, int Kd)
{
  __shared__ u16 As[128 * 32];
  __shared__ u16 Bs[128 * 32];
  const int tid = threadIdx.x;
  const int lane = tid & 63, wid = tid >> 6;
  const int wr = wid >> 1, wc = wid & 1;
  const int rowBase = blockIdx.y * 128;
  const int colBase = blockIdx.x * 128;

  f32x4 acc[4][4] = {};

  // staging: thread t covers LDS bytes [t*16, t*16+16) = row t/4, k-elems (t%4)*8
  const int srow = tid >> 2;
  const int skb  = (tid & 3) * 8;
  const u16* ag0 = A  + (size_t)(rowBase + srow) * Kd + skb;
  const u16* ag1 = A  + (size_t)(rowBase + 64 + srow) * Kd + skb;
  const u16* bg0 = BT + (size_t)(colBase + srow) * Kd + skb;
  const u16* bg1 = BT + (size_t)(colBase + 64 + srow) * Kd + skb;
  u16* la0 = As + tid * 8;
  u16* la1 = As + 2048 + tid * 8;
  u16* lb0 = Bs + tid * 8;
  u16* lb1 = Bs + 2048 + tid * 8;

  const int fr = lane & 15, fq = lane >> 4;

  for (int k0 = 0; k0 < Kd; k0 += 32) {
    gload16(ag0 + k0, la0);
    gload16(ag1 + k0, la1);
    gload16(bg0 + k0, lb0);
    gload16(bg1 + k0, lb1);
    __syncthreads();               // drains vmcnt before barrier
    f32x4 af[4], bf_[4];
    #pragma unroll
    for (int m = 0; m < 4; ++m)
      af[m] = *(const f32x4*)(As + (wr * 64 + m * 16 + fr) * 32 + fq * 8);
    #pragma unroll
    for (int n = 0; n < 4; ++n)
      bf_[n] = *(const f32x4*)(Bs + (wc * 64 + n * 16 + fr) * 32 + fq * 8);
    #pragma unroll
    for (int m = 0; m < 4; ++m)
      #pragma unroll
      for (int n = 0; n < 4; ++n)
        asm("v_mfma_f32_16x16x32_bf16 %0, %1, %2, %0"
            : "+v"(acc[m][n]) : "v"(af[m]), "v"(bf_[n]));
    __syncthreads();               // LDS reads done before next stage
  }

  #pragma unroll
  for (int m = 0; m < 4; ++m) {
    #pragma unroll
    for (int n = 0; n < 4; ++n) {
      const int col = colBase + wc * 64 + n * 16 + fr;
      const float bv = bias[col];
      #pragma unroll
      for (int r = 0; r < 4; ++r) {
        const int row = rowBase + wr * 64 + m * 16 + fq * 4 + r;
        float val = acc[m][n][r] + bv;
        if (ACT == ACT_ELU1)      val = (val >= 0.f) ? (val + 1.f) : expf(val);
        else if (ACT == ACT_GELU) val = 0.5f * val * (1.f + erff(val * 0.70710678118f));
        if (RES) val += res[(size_t)row * N + col];
        if (F32OUT) ((float*)Cout)[(size_t)row * N + col] = val;
        else        ((u16*)Cout)[(size_t)row * N + col] = f2bf(val);
      }
    }
  }
}

// ---------------- decay head: llam[row][h] = log(max(sigmoid(xn@dec_w+b),1e-8)) ----------------
__global__ __launch_bounds__(256) void declam_kernel(
    const float* __restrict__ xn, const float* __restrict__ dec_w,
    const float* __restrict__ dec_b, float* __restrict__ llam)
{
  const int row = blockIdx.x;
  const int tid = threadIdx.x;
  const int h = tid & 15, part = tid >> 4;
  const float* xr = xn + (size_t)row * Dq;
  float s = 0.f;
  #pragma unroll 4
  for (int i = 0; i < 64; ++i) {
    const int d = part * 64 + i;
    s += xr[d] * dec_w[d * Hq + h];
  }
  __shared__ float ps[256];
  ps[tid] = s;
  __syncthreads();
  if (tid < 16) {
    float t = dec_b[tid];
    #pragma unroll
    for (int p = 0; p < 16; ++p) t += ps[p * 16 + tid];
    float lam = 1.f / (1.f + expf(-t));
    lam = fmaxf(lam, 1e-8f);
    llam[(size_t)row * Hq + tid] = logf(lam);
  }
}

// ---------------- LION phase A: per-chunk intra output + state deltas ----------------
__global__ __launch_bounds__(256) void lion_chunk_kernel(
    const u16* __restrict__ qb, const u16* __restrict__ kb,
    const u16* __restrict__ vb, const float* __restrict__ llam,
    float* __restrict__ intra, float* __restrict__ dS,
    float* __restrict__ dR, float* __restrict__ lwout)
{
  const int c  = blockIdx.x;
  const int bh = blockIdx.y;
  const int b = bh >> 4, h = bh & 15;
  const int tid = threadIdx.x;
  const int tx = tid & 15, ty = tid >> 4;

  __shared__ float qs[64 * 65];   // later aliased as the A-coeff matrix
  __shared__ float ks[64 * 65];
  __shared__ float vs[64 * 65];
  __shared__ float lw[64];
  __shared__ float e1[64], e2[64];

  const size_t rowbase = ((size_t)(b * Tq + c * 64)) * Dq + h * 64;
  #pragma unroll
  for (int r = 0; r < 2; ++r) {
    const int s = tid + r * 256;              // 0..511
    const int u = s >> 3, e8 = (s & 7) << 3;
    const uint4 qv = *(const uint4*)(qb + rowbase + (size_t)u * Dq + e8);
    const uint4 kv = *(const uint4*)(kb + rowbase + (size_t)u * Dq + e8);
    const uint4 vv = *(const uint4*)(vb + rowbase + (size_t)u * Dq + e8);
    const int o = u * 65 + e8;
    qs[o+0]=bflo(qv.x); qs[o+1]=bfhi(qv.x); qs[o+2]=bflo(qv.y); qs[o+3]=bfhi(qv.y);
    qs[o+4]=bflo(qv.z); qs[o+5]=bfhi(qv.z); qs[o+6]=bflo(qv.w); qs[o+7]=bfhi(qv.w);
    ks[o+0]=bflo(kv.x); ks[o+1]=bfhi(kv.x); ks[o+2]=bflo(kv.y); ks[o+3]=bfhi(kv.y);
    ks[o+4]=bflo(kv.z); ks[o+5]=bfhi(kv.z); ks[o+6]=bflo(kv.w); ks[o+7]=bfhi(kv.w);
    vs[o+0]=bflo(vv.x); vs[o+1]=bfhi(vv.x); vs[o+2]=bflo(vv.y); vs[o+3]=bfhi(vv.y);
    vs[o+4]=bflo(vv.z); vs[o+5]=bfhi(vv.z); vs[o+6]=bflo(vv.w); vs[o+7]=bfhi(vv.w);
  }
  if (tid < 64) {   // wave 0: inclusive scan of log-lambda over the chunk
    const float lg = llam[((size_t)(b * Tq + c * 64 + tid)) * Hq + h];
    float sum = lg;
    #pragma unroll
    for (int off = 1; off < 64; off <<= 1) {
      const float y = __shfl_up(sum, off);
      if (tid >= off) sum += y;
    }
    lw[tid] = sum;
    const float lwE = __shfl(sum, 63);
    e1[tid] = expf(lwE - sum);   // decay from t to chunk end
    e2[tid] = expf(sum);         // decay from chunk start through t
    lwout[((size_t)bh * NCHUNK + c) * 64 + tid] = sum;
  }
  __syncthreads();

  // ---- A = (Q Kᵀ) ∘ exp(-|lw_i - lw_j|)
  float am[4][4] = {};
  for (int kk = 0; kk < 64; ++kk) {
    float a[4], bv_[4];
    #pragma unroll
    for (int i = 0; i < 4; ++i) a[i]  = qs[(ty * 4 + i) * 65 + kk];
    #pragma unroll
    for (int j = 0; j < 4; ++j) bv_[j] = ks[(tx * 4 + j) * 65 + kk];
    #pragma unroll
    for (int i = 0; i < 4; ++i)
      #pragma unroll
      for (int j = 0; j < 4; ++j)
        am[i][j] += a[i] * bv_[j];
  }
  __syncthreads();                 // all reads of qs done
  float* Am = qs;                  // alias
  #pragma unroll
  for (int i = 0; i < 4; ++i) {
    const float lwi = lw[ty * 4 + i];
    #pragma unroll
    for (int j = 0; j < 4; ++j)
      Am[(ty * 4 + i) * 65 + tx * 4 + j] = am[i][j] * expf(-fabsf(lwi - lw[tx * 4 + j]));
  }
  __syncthreads();

  const size_t obase = ((size_t)bh * NCHUNK + c) * STW;

  // ---- intra = A @ V_ext
  {
    float acc2[4][4] = {};
    for (int uj = 0; uj < 64; ++uj) {
      float a[4], bv_[4];
      #pragma unroll
      for (int i = 0; i < 4; ++i) a[i]  = Am[(ty * 4 + i) * 65 + uj];
      #pragma unroll
      for (int j = 0; j < 4; ++j) bv_[j] = vs[uj * 65 + tx * 4 + j];
      #pragma unroll
      for (int i = 0; i < 4; ++i)
        #pragma unroll
        for (int j = 0; j < 4; ++j)
          acc2[i][j] += a[i] * bv_[j];
    }
    #pragma unroll
    for (int i = 0; i < 4; ++i)
      #pragma unroll
      for (int j = 0; j < 4; ++j)
        intra[obase + (ty * 4 + i) * 65 + tx * 4 + j] = acc2[i][j];
  }
  if (tid < 64) {
    float s = 0.f;
    for (int uj = 0; uj < 64; ++uj) s += Am[tid * 65 + uj];
    intra[obase + tid * 65 + 64] = s;
  }

  // ---- dS[k][kv] = Σ_u e1[u]·k_u[k]·v_u[kv] ; dR with e2
  {
    float accS[4][4] = {}, accR[4][4] = {};
    for (int u = 0; u < 64; ++u) {
      const float w1 = e1[u], w2 = e2[u];
      float kr[4], vr[4];
      #pragma unroll
      for (int i = 0; i < 4; ++i) kr[i] = ks[u * 65 + ty * 4 + i];
      #pragma unroll
      for (int j = 0; j < 4; ++j) vr[j] = vs[u * 65 + tx * 4 + j];
      #pragma unroll
      for (int i = 0; i < 4; ++i)
        #pragma unroll
        for (int j = 0; j < 4; ++j) {
          const float p = kr[i] * vr[j];
          accS[i][j] += w1 * p;
          accR[i][j] += w2 * p;
        }
    }
    #pragma unroll
    for (int i = 0; i < 4; ++i)
      #pragma unroll
      for (int j = 0; j < 4; ++j) {
        const size_t idx = obase + (ty * 4 + i) * 65 + tx * 4 + j;
        dS[idx] = accS[i][j];
        dR[idx] = accR[i][j];
      }
  }
  if (tid < 64) {
    float sS = 0.f, sR = 0.f;
    for (int u = 0; u < 64; ++u) {
      const float kv_ = ks[u * 65 + tid];
      sS += e1[u] * kv_;
      sR += e2[u] * kv_;
    }
    dS[obase + tid * 65 + 64] = sS;
    dR[obase + tid * 65 + 64] = sR;
  }
}

// ---------------- LION phase B: sequential chunk-state combine (in-place) ----------------
__global__ __launch_bounds__(256) void lion_state_kernel(
    float* __restrict__ dS, float* __restrict__ dR,
    const float* __restrict__ lwbuf)
{
  const int bh  = blockIdx.x >> 1;
  const int dir = blockIdx.x & 1;
  const int tid = threadIdx.x;
  float st[17];
  #pragma unroll
  for (int r = 0; r < 17; ++r) st[r] = 0.f;
  if (dir == 0) {
    for (int c = 0; c < NCHUNK; ++c) {
      const float d = expf(lwbuf[((size_t)bh * NCHUNK + c) * 64 + 63]);
      const size_t base = ((size_t)bh * NCHUNK + c) * STW;
      #pragma unroll
      for (int r = 0; r < 17; ++r) {
        const int e = tid + r * 256;
        if (e < STW) {
          const float tmp = dS[base + e];
          dS[base + e] = st[r];
          st[r] = fmaf(d, st[r], tmp);
        }
      }
    }
  } else {
    for (int c = NCHUNK - 1; c >= 0; --c) {
      const float d = expf(lwbuf[((size_t)bh * NCHUNK + c) * 64 + 63]);
      const size_t base = ((size_t)bh * NCHUNK + c) * STW;
      #pragma unroll
      for (int r = 0; r < 17; ++r) {
        const int e = tid + r * 256;
        if (e < STW) {
          const float tmp = dR[base + e];
          dR[base + e] = st[r];
          st[r] = fmaf(d, st[r], tmp);
        }
      }
    }
  }
}

// ---------------- LION phase C: cross-chunk terms + normalize -> attn (bf16) ----------------
__global__ __launch_bounds__(256) void lion_cross_kernel(
    const u16* __restrict__ qb, const float* __restrict__ intra,
    const float* __restrict__ Sst, const float* __restrict__ Rst,
    const float* __restrict__ lwbuf, u16* __restrict__ attn)
{
  const int c  = blockIdx.x;
  const int bh = blockIdx.y;
  const int b = bh >> 4, h = bh & 15;
  const int tid = threadIdx.x;
  const int tx = tid & 15, ty = tid >> 4;

  __shared__ float qs[64 * 65];    // later aliased as out tile
  __shared__ float Ss[STW];
  __shared__ float Rs[STW];
  __shared__ float lw[64];

  const size_t rowbase = ((size_t)(b * Tq + c * 64)) * Dq + h * 64;
  #pragma unroll
  for (int r = 0; r < 2; ++r) {
    const int s = tid + r * 256;
    const int u = s >> 3, e8 = (s & 7) << 3;
    const uint4 qv = *(const uint4*)(qb + rowbase + (size_t)u * Dq + e8);
    const int o = u * 65 + e8;
    qs[o+0]=bflo(qv.x); qs[o+1]=bfhi(qv.x); qs[o+2]=bflo(qv.y); qs[o+3]=bfhi(qv.y);
    qs[o+4]=bflo(qv.z); qs[o+5]=bfhi(qv.z); qs[o+6]=bflo(qv.w); qs[o+7]=bfhi(qv.w);
  }
  const size_t obase = ((size_t)bh * NCHUNK + c) * STW;
  for (int e = tid; e < STW; e += 256) {
    Ss[e] = Sst[obase + e];
    Rs[e] = Rst[obase + e];
  }
  if (tid < 64) lw[tid] = lwbuf[((size_t)bh * NCHUNK + c) * 64 + tid];
  __syncthreads();
  const float lwE = lw[63];

  float aS[4][4] = {}, aR[4][4] = {};
  for (int kk = 0; kk < 64; ++kk) {
    float a[4], s4[4], r4[4];
    #pragma unroll
    for (int i = 0; i < 4; ++i) a[i]  = qs[(ty * 4 + i) * 65 + kk];
    #pragma unroll
    for (int j = 0; j < 4; ++j) { s4[j] = Ss[kk * 65 + tx * 4 + j]; r4[j] = Rs[kk * 65 + tx * 4 + j]; }
    #pragma unroll
    for (int i = 0; i < 4; ++i)
      #pragma unroll
      for (int j = 0; j < 4; ++j) {
        aS[i][j] += a[i] * s4[j];
        aR[i][j] += a[i] * r4[j];
      }
  }
  float dnS = 0.f, dnR = 0.f;
  if (tid < 64) {
    for (int kk = 0; kk < 64; ++kk) {
      const float qv = qs[tid * 65 + kk];
      dnS += qv * Ss[kk * 65 + 64];
      dnR += qv * Rs[kk * 65 + 64];
    }
  }
  __syncthreads();               // all reads of qs done
  float* outb = qs;              // alias
  #pragma unroll
  for (int i = 0; i < 4; ++i) {
    const float ef = expf(lw[ty * 4 + i]);
    const float eb = expf(lwE - lw[ty * 4 + i]);
    #pragma unroll
    for (int j = 0; j < 4; ++j) {
      const int idx = (ty * 4 + i) * 65 + tx * 4 + j;
      outb[idx] = intra[obase + idx] + ef * aS[i][j] + eb * aR[i][j];
    }
  }
  if (tid < 64) {
    outb[tid * 65 + 64] = intra[obase + tid * 65 + 64]
                        + expf(lw[tid]) * dnS + expf(lwE - lw[tid]) * dnR;
  }
  __syncthreads();
  for (int e = tid; e < 4096; e += 256) {
    const int ui = e >> 6, kk = e & 63;
    const float den = fmaxf(outb[ui * 65 + 64], 1e-6f);
    attn[rowbase + (size_t)ui * Dq + kk] = f2bf(outb[ui * 65 + kk] / den);
  }
}

// ---------------- launch ----------------
extern "C" void kernel_launch(void* const* d_in, const int* in_sizes, int n_in,
                              void* d_out, int out_size, void* d_ws, size_t ws_size,
                              hipStream_t stream)
{
  const float* x     = (const float*)d_in[0];
  const float* q_w   = (const float*)d_in[1];
  const float* q_b   = (const float*)d_in[2];
  const float* k_w   = (const float*)d_in[3];
  const float* k_b   = (const float*)d_in[4];
  const float* v_w   = (const float*)d_in[5];
  const float* v_b   = (const float*)d_in[6];
  const float* o_w   = (const float*)d_in[7];
  const float* o_b   = (const float*)d_in[8];
  const float* ln1_w = (const float*)d_in[9];
  const float* ln1_b = (const float*)d_in[10];
  const float* ln2_w = (const float*)d_in[11];
  const float* ln2_b = (const float*)d_in[12];
  const float* dec_w = (const float*)d_in[13];
  const float* dec_b = (const float*)d_in[14];
  const float* f1_w  = (const float*)d_in[15];
  const float* f1_b  = (const float*)d_in[16];
  const float* f2_w  = (const float*)d_in[17];
  const float* f2_b  = (const float*)d_in[18];
  float* out = (float*)d_out;
  float* ws  = (float*)d_ws;

  size_t o = 0;
  float* xn    = ws + o; o += (size_t)ROWS * Dq;        // fp32 LN1 out (declam)
  float* xa    = ws + o; o += (size_t)ROWS * Dq;        // fp32 post-attn residual
  u16*   xnb   = (u16*)(ws + o); o += (size_t)ROWS * Dq / 2;
  u16*   qbuf  = (u16*)(ws + o); o += (size_t)ROWS * Dq / 2;
  u16*   kbuf  = (u16*)(ws + o); o += (size_t)ROWS * Dq / 2;
  u16*   vbuf  = (u16*)(ws + o); o += (size_t)ROWS * Dq / 2;
  u16*   attnb = (u16*)(ws + o); o += (size_t)ROWS * Dq / 2;
  u16*   hb    = qbuf;  // FFN hidden 4096x4096 bf16 = 32 MB aliases qbuf..attnb (dead then)
  float* llam  = ws + o; o += (size_t)ROWS * Hq;
  float* lwb   = ws + o; o += (size_t)32 * NCHUNK * 64;
  float* dSb   = ws + o; o += (size_t)32 * NCHUNK * STW;
  float* dRb   = ws + o; o += (size_t)32 * NCHUNK * STW;
  float* intrab= ws + o; o += (size_t)32 * NCHUNK * STW;
  u16*   x2b   = (u16*)intrab;  // LN2 out aliases intrab (dead after lion_cross)
  u16*   qwT   = (u16*)(ws + o); o += (size_t)Dq * Dq / 2;
  u16*   kwT   = (u16*)(ws + o); o += (size_t)Dq * Dq / 2;
  u16*   vwT   = (u16*)(ws + o); o += (size_t)Dq * Dq / 2;
  u16*   owT   = (u16*)(ws + o); o += (size_t)Dq * Dq / 2;
  u16*   f1T   = (u16*)(ws + o); o += (size_t)Dq * FFNq / 2;
  u16*   f2T   = (u16*)(ws + o); o += (size_t)Dq * FFNq / 2;

  // weight bf16 transpose
  wconv<<<dim3(16, 16), 256, 0, stream>>>(q_w, qwT, Dq, Dq);
  wconv<<<dim3(16, 16), 256, 0, stream>>>(k_w, kwT, Dq, Dq);
  wconv<<<dim3(16, 16), 256, 0, stream>>>(v_w, vwT, Dq, Dq);
  wconv<<<dim3(16, 16), 256, 0, stream>>>(o_w, owT, Dq, Dq);
  wconv<<<dim3(64, 16), 256, 0, stream>>>(f1_w, f1T, Dq, FFNq);
  wconv<<<dim3(16, 64), 256, 0, stream>>>(f2_w, f2T, FFNq, Dq);

  ln_kernel<true><<<ROWS, 256, 0, stream>>>(x, ln1_w, ln1_b, xn, xnb);
  mgemm<ACT_ELU1, false, false><<<dim3(8, 32), 256, 0, stream>>>(xnb, qwT, q_b, nullptr, qbuf, ROWS, Dq, Dq);
  mgemm<ACT_ELU1, false, false><<<dim3(8, 32), 256, 0, stream>>>(xnb, kwT, k_b, nullptr, kbuf, ROWS, Dq, Dq);
  mgemm<ACT_NONE, false, false><<<dim3(8, 32), 256, 0, stream>>>(xnb, vwT, v_b, nullptr, vbuf, ROWS, Dq, Dq);
  declam_kernel<<<ROWS, 256, 0, stream>>>(xn, dec_w, dec_b, llam);

  lion_chunk_kernel<<<dim3(NCHUNK, 32), 256, 0, stream>>>(qbuf, kbuf, vbuf, llam, intrab, dSb, dRb, lwb);
  lion_state_kernel<<<64, 256, 0, stream>>>(dSb, dRb, lwb);
  lion_cross_kernel<<<dim3(NCHUNK, 32), 256, 0, stream>>>(qbuf, intrab, dSb, dRb, lwb, attnb);

  mgemm<ACT_NONE, true, true><<<dim3(8, 32), 256, 0, stream>>>(attnb, owT, o_b, x, xa, ROWS, Dq, Dq);
  ln_kernel<false><<<ROWS, 256, 0, stream>>>(xa, ln2_w, ln2_b, nullptr, x2b);
  mgemm<ACT_GELU, false, false><<<dim3(32, 32), 256, 0, stream>>>(x2b, f1T, f1_b, nullptr, hb, ROWS, FFNq, Dq);
  mgemm<ACT_NONE, true, true><<<dim3(8, 32), 256, 0, stream>>>(hb, f2T, f2_b, xa, out, ROWS, Dq, FFNq);
}

// Round 3
// 388.883 us; speedup vs baseline: 4.2028x; 1.1273x over previous
//
#include <hip/hip_runtime.h>
#include <cstdint>

#define Bq 2
#define Tq 2048
#define Dq 1024
#define Hq 16
#define Kq 64
#define FFNq 4096
#define NCHUNK 32
#define ROWS (Bq*Tq)   // 4096
#define STW 4160       // 64*65 state/tile words

typedef unsigned short u16;
typedef __attribute__((ext_vector_type(4))) float f32x4;

enum { ACT_NONE = 0, ACT_ELU1 = 1, ACT_GELU = 2 };

__device__ __forceinline__ u16 f2bf(float f) {
  uint32_t u = __float_as_uint(f);
  uint32_t r = (u + 0x7FFFu + ((u >> 16) & 1u)) >> 16;
  return (u16)r;
}
__device__ __forceinline__ float bflo(uint32_t w) { return __uint_as_float(w << 16); }
__device__ __forceinline__ float bfhi(uint32_t w) { return __uint_as_float(w & 0xffff0000u); }

__device__ __forceinline__ void gload16(const void* g, void* l) {
  __builtin_amdgcn_global_load_lds(
      (const __attribute__((address_space(1))) uint32_t*)g,
      (__attribute__((address_space(3))) uint32_t*)l, 16, 0, 0);
}

// bijective XCD swizzle (nwg % 8 == 0 for all our grids)
__device__ __forceinline__ void xcd_swizzle(int& bx, int& by) {
  const int gx = gridDim.x;
  const int nwg = gx * gridDim.y;
  int flat = by * gx + bx;
  flat = (flat & 7) * (nwg >> 3) + (flat >> 3);
  bx = flat % gx;
  by = flat / gx;
}

// ---------------- weight convert + transpose: src fp32 [Kd][N] -> dst bf16 [N][Kd] ----------------
__global__ __launch_bounds__(256) void wconv(const float* __restrict__ src,
                                             u16* __restrict__ dst, int Kd, int N)
{
  __shared__ float t[64][65];
  const int n0 = blockIdx.x * 64, k0 = blockIdx.y * 64;
  const int tid = threadIdx.x;
  #pragma unroll
  for (int r = 0; r < 4; ++r) {
    const int s = tid + r * 256;           // 0..1023
    const int kk = s >> 4, nn = (s & 15) << 2;
    const float4 v = *(const float4*)(src + (size_t)(k0 + kk) * N + n0 + nn);
    t[kk][nn] = v.x; t[kk][nn+1] = v.y; t[kk][nn+2] = v.z; t[kk][nn+3] = v.w;
  }
  __syncthreads();
  const int n = tid >> 2;
  const int ks = (tid & 3) << 4;
  uint32_t pk[8];
  #pragma unroll
  for (int j = 0; j < 8; ++j) {
    const float a = t[ks + 2*j][n];
    const float c = t[ks + 2*j + 1][n];
    pk[j] = (uint32_t)f2bf(a) | ((uint32_t)f2bf(c) << 16);
  }
  u16* drow = dst + (size_t)(n0 + n) * Kd + k0 + ks;
  *(uint4*)(drow)     = make_uint4(pk[0], pk[1], pk[2], pk[3]);
  *(uint4*)(drow + 8) = make_uint4(pk[4], pk[5], pk[6], pk[7]);
}

// ---------------- LayerNorm: fp32 in, bf16 out (+ optional fp32 out) ----------------
template<bool F32OUT>
__global__ __launch_bounds__(256) void ln_kernel(
    const float* __restrict__ x, const float* __restrict__ w,
    const float* __restrict__ b, float* __restrict__ outf, u16* __restrict__ outb)
{
  const int row = blockIdx.x;
  const int tid = threadIdx.x;
  const float* xr = x + (size_t)row * Dq;
  float4 v = *(const float4*)(xr + tid * 4);
  float s  = v.x + v.y + v.z + v.w;
  float s2 = v.x*v.x + v.y*v.y + v.z*v.z + v.w*v.w;
  #pragma unroll
  for (int off = 32; off > 0; off >>= 1) {
    s  += __shfl_down(s,  off);
    s2 += __shfl_down(s2, off);
  }
  __shared__ float rs[4], rs2[4];
  const int wid = tid >> 6, lane = tid & 63;
  if (lane == 0) { rs[wid] = s; rs2[wid] = s2; }
  __syncthreads();
  const float ts  = rs[0] + rs[1] + rs[2] + rs[3];
  const float ts2 = rs2[0] + rs2[1] + rs2[2] + rs2[3];
  const float mean = ts * (1.f / Dq);
  const float var  = ts2 * (1.f / Dq) - mean * mean;
  const float rstd = rsqrtf(var + 1e-5f);
  const float4 wv = *(const float4*)(w + tid * 4);
  const float4 bv = *(const float4*)(b + tid * 4);
  float4 o;
  o.x = (v.x - mean) * rstd * wv.x + bv.x;
  o.y = (v.y - mean) * rstd * wv.y + bv.y;
  o.z = (v.z - mean) * rstd * wv.z + bv.z;
  o.w = (v.w - mean) * rstd * wv.w + bv.w;
  if (F32OUT) *(float4*)(outf + (size_t)row * Dq + tid * 4) = o;
  uint2 p;
  p.x = (uint32_t)f2bf(o.x) | ((uint32_t)f2bf(o.y) << 16);
  p.y = (uint32_t)f2bf(o.z) | ((uint32_t)f2bf(o.w) << 16);
  *(uint2*)(outb + (size_t)row * Dq + tid * 4) = p;
}

// ---------------- bf16 MFMA GEMM, 2-phase double-buffered staging ----------------
// A [M][Kd] bf16, BT [N][Kd] bf16. 128x128 tile, BK=32, 256 thr (4 waves 2x2).
template<int ACT, bool RES, bool F32OUT>
__global__ __launch_bounds__(256) void mgemm(
    const u16* __restrict__ A, const u16* __restrict__ BT,
    const float* __restrict__ bias, const float* __restrict__ res,
    void* __restrict__ Cout, int M, int N, int Kd)
{
  __shared__ u16 As[2][128 * 32];
  __shared__ u16 Bs[2][128 * 32];
  const int tid = threadIdx.x;
  const int lane = tid & 63, wid = tid >> 6;
  const int wr = wid >> 1, wc = wid & 1;
  int bx = blockIdx.x, by = blockIdx.y;
  xcd_swizzle(bx, by);
  const int rowBase = by * 128;
  const int colBase = bx * 128;

  f32x4 acc[4][4] = {};

  const int srow = tid >> 2;
  const int skb  = (tid & 3) * 8;
  const u16* ag0 = A  + (size_t)(rowBase + srow) * Kd + skb;
  const u16* ag1 = A  + (size_t)(rowBase + 64 + srow) * Kd + skb;
  const u16* bg0 = BT + (size_t)(colBase + srow) * Kd + skb;
  const u16* bg1 = BT + (size_t)(colBase + 64 + srow) * Kd + skb;

  const int fr = lane & 15, fq = lane >> 4;

#define STAGE(buf, k0)                                  \
  do {                                                  \
    gload16(ag0 + (k0), &As[buf][tid * 8]);             \
    gload16(ag1 + (k0), &As[buf][2048 + tid * 8]);      \
    gload16(bg0 + (k0), &Bs[buf][tid * 8]);             \
    gload16(bg1 + (k0), &Bs[buf][2048 + tid * 8]);      \
  } while (0)

  STAGE(0, 0);
  __syncthreads();
  int cur = 0;
  for (int k0 = 0; k0 < Kd; k0 += 32) {
    if (k0 + 32 < Kd) STAGE(cur ^ 1, k0 + 32);   // next tile flies under compute
    f32x4 af[4], bf_[4];
    #pragma unroll
    for (int m = 0; m < 4; ++m)
      af[m] = *(const f32x4*)(&As[cur][(wr * 64 + m * 16 + fr) * 32 + fq * 8]);
    #pragma unroll
    for (int n = 0; n < 4; ++n)
      bf_[n] = *(const f32x4*)(&Bs[cur][(wc * 64 + n * 16 + fr) * 32 + fq * 8]);
    #pragma unroll
    for (int m = 0; m < 4; ++m)
      #pragma unroll
      for (int n = 0; n < 4; ++n)
        asm("v_mfma_f32_16x16x32_bf16 %0, %1, %2, %0"
            : "+v"(acc[m][n]) : "v"(af[m]), "v"(bf_[n]));
    __syncthreads();               // drains vmcnt(0): next buffer ready
    cur ^= 1;
  }
#undef STAGE

  #pragma unroll
  for (int m = 0; m < 4; ++m) {
    #pragma unroll
    for (int n = 0; n < 4; ++n) {
      const int col = colBase + wc * 64 + n * 16 + fr;
      const float bv = bias[col];
      #pragma unroll
      for (int r = 0; r < 4; ++r) {
        const int row = rowBase + wr * 64 + m * 16 + fq * 4 + r;
        float val = acc[m][n][r] + bv;
        if (ACT == ACT_ELU1)      val = (val >= 0.f) ? (val + 1.f) : expf(val);
        else if (ACT == ACT_GELU) val = 0.5f * val * (1.f + erff(val * 0.70710678118f));
        if (RES) val += res[(size_t)row * N + col];
        if (F32OUT) ((float*)Cout)[(size_t)row * N + col] = val;
        else        ((u16*)Cout)[(size_t)row * N + col] = f2bf(val);
      }
    }
  }
}

// ---------------- fused QKV GEMM: N=3072 over concat [qwT|kwT|vwT], routed epilogue ----------------
__global__ __launch_bounds__(256) void mgemm_qkv(
    const u16* __restrict__ A, const u16* __restrict__ BT,
    const float* __restrict__ q_b, const float* __restrict__ k_b,
    const float* __restrict__ v_b,
    u16* __restrict__ qo, u16* __restrict__ ko, u16* __restrict__ vo)
{
  const int Kd = Dq;
  __shared__ u16 As[2][128 * 32];
  __shared__ u16 Bs[2][128 * 32];
  const int tid = threadIdx.x;
  const int lane = tid & 63, wid = tid >> 6;
  const int wr = wid >> 1, wc = wid & 1;
  int bx = blockIdx.x, by = blockIdx.y;
  xcd_swizzle(bx, by);
  const int rowBase = by * 128;
  const int colBase = bx * 128;

  f32x4 acc[4][4] = {};

  const int srow = tid >> 2;
  const int skb  = (tid & 3) * 8;
  const u16* ag0 = A  + (size_t)(rowBase + srow) * Kd + skb;
  const u16* ag1 = A  + (size_t)(rowBase + 64 + srow) * Kd + skb;
  const u16* bg0 = BT + (size_t)(colBase + srow) * Kd + skb;
  const u16* bg1 = BT + (size_t)(colBase + 64 + srow) * Kd + skb;

  const int fr = lane & 15, fq = lane >> 4;

#define STAGE(buf, k0)                                  \
  do {                                                  \
    gload16(ag0 + (k0), &As[buf][tid * 8]);             \
    gload16(ag1 + (k0), &As[buf][2048 + tid * 8]);      \
    gload16(bg0 + (k0), &Bs[buf][tid * 8]);             \
    gload16(bg1 + (k0), &Bs[buf][2048 + tid * 8]);      \
  } while (0)

  STAGE(0, 0);
  __syncthreads();
  int cur = 0;
  for (int k0 = 0; k0 < Kd; k0 += 32) {
    if (k0 + 32 < Kd) STAGE(cur ^ 1, k0 + 32);
    f32x4 af[4], bf_[4];
    #pragma unroll
    for (int m = 0; m < 4; ++m)
      af[m] = *(const f32x4*)(&As[cur][(wr * 64 + m * 16 + fr) * 32 + fq * 8]);
    #pragma unroll
    for (int n = 0; n < 4; ++n)
      bf_[n] = *(const f32x4*)(&Bs[cur][(wc * 64 + n * 16 + fr) * 32 + fq * 8]);
    #pragma unroll
    for (int m = 0; m < 4; ++m)
      #pragma unroll
      for (int n = 0; n < 4; ++n)
        asm("v_mfma_f32_16x16x32_bf16 %0, %1, %2, %0"
            : "+v"(acc[m][n]) : "v"(af[m]), "v"(bf_[n]));
    __syncthreads();
    cur ^= 1;
  }
#undef STAGE

  const int wtype = colBase >> 10;                 // 0=q, 1=k, 2=v (block-uniform)
  const float* bp = (wtype == 0) ? q_b : (wtype == 1) ? k_b : v_b;
  u16* outp = (wtype == 0) ? qo : (wtype == 1) ? ko : vo;
  const int colB = colBase - (wtype << 10);
  #pragma unroll
  for (int m = 0; m < 4; ++m) {
    #pragma unroll
    for (int n = 0; n < 4; ++n) {
      const int col = colB + wc * 64 + n * 16 + fr;
      const float bv = bp[col];
      #pragma unroll
      for (int r = 0; r < 4; ++r) {
        const int row = rowBase + wr * 64 + m * 16 + fq * 4 + r;
        float val = acc[m][n][r] + bv;
        if (wtype < 2) val = (val >= 0.f) ? (val + 1.f) : expf(val);
        outp[(size_t)row * Dq + col] = f2bf(val);
      }
    }
  }
}

// ---------------- decay head ----------------
__global__ __launch_bounds__(256) void declam_kernel(
    const float* __restrict__ xn, const float* __restrict__ dec_w,
    const float* __restrict__ dec_b, float* __restrict__ llam)
{
  const int row = blockIdx.x;
  const int tid = threadIdx.x;
  const int h = tid & 15, part = tid >> 4;
  const float* xr = xn + (size_t)row * Dq;
  float s = 0.f;
  #pragma unroll 4
  for (int i = 0; i < 64; ++i) {
    const int d = part * 64 + i;
    s += xr[d] * dec_w[d * Hq + h];
  }
  __shared__ float ps[256];
  ps[tid] = s;
  __syncthreads();
  if (tid < 16) {
    float t = dec_b[tid];
    #pragma unroll
    for (int p = 0; p < 16; ++p) t += ps[p * 16 + tid];
    float lam = 1.f / (1.f + expf(-t));
    lam = fmaxf(lam, 1e-8f);
    llam[(size_t)row * Hq + tid] = logf(lam);
  }
}

// ---------------- LION phase A ----------------
__global__ __launch_bounds__(256) void lion_chunk_kernel(
    const u16* __restrict__ qb, const u16* __restrict__ kb,
    const u16* __restrict__ vb, const float* __restrict__ llam,
    float* __restrict__ intra, float* __restrict__ dS,
    float* __restrict__ dR, float* __restrict__ lwout)
{
  const int c  = blockIdx.x;
  const int bh = blockIdx.y;
  const int b = bh >> 4, h = bh & 15;
  const int tid = threadIdx.x;
  const int tx = tid & 15, ty = tid >> 4;

  __shared__ float qs[64 * 65];
  __shared__ float ks[64 * 65];
  __shared__ float vs[64 * 65];
  __shared__ float lw[64];
  __shared__ float e1[64], e2[64];

  const size_t rowbase = ((size_t)(b * Tq + c * 64)) * Dq + h * 64;
  #pragma unroll
  for (int r = 0; r < 2; ++r) {
    const int s = tid + r * 256;
    const int u = s >> 3, e8 = (s & 7) << 3;
    const uint4 qv = *(const uint4*)(qb + rowbase + (size_t)u * Dq + e8);
    const uint4 kv = *(const uint4*)(kb + rowbase + (size_t)u * Dq + e8);
    const uint4 vv = *(const uint4*)(vb + rowbase + (size_t)u * Dq + e8);
    const int o = u * 65 + e8;
    qs[o+0]=bflo(qv.x); qs[o+1]=bfhi(qv.x); qs[o+2]=bflo(qv.y); qs[o+3]=bfhi(qv.y);
    qs[o+4]=bflo(qv.z); qs[o+5]=bfhi(qv.z); qs[o+6]=bflo(qv.w); qs[o+7]=bfhi(qv.w);
    ks[o+0]=bflo(kv.x); ks[o+1]=bfhi(kv.x); ks[o+2]=bflo(kv.y); ks[o+3]=bfhi(kv.y);
    ks[o+4]=bflo(kv.z); ks[o+5]=bfhi(kv.z); ks[o+6]=bflo(kv.w); ks[o+7]=bfhi(kv.w);
    vs[o+0]=bflo(vv.x); vs[o+1]=bfhi(vv.x); vs[o+2]=bflo(vv.y); vs[o+3]=bfhi(vv.y);
    vs[o+4]=bflo(vv.z); vs[o+5]=bfhi(vv.z); vs[o+6]=bflo(vv.w); vs[o+7]=bfhi(vv.w);
  }
  if (tid < 64) {
    const float lg = llam[((size_t)(b * Tq + c * 64 + tid)) * Hq + h];
    float sum = lg;
    #pragma unroll
    for (int off = 1; off < 64; off <<= 1) {
      const float y = __shfl_up(sum, off);
      if (tid >= off) sum += y;
    }
    lw[tid] = sum;
    const float lwE = __shfl(sum, 63);
    e1[tid] = expf(lwE - sum);
    e2[tid] = expf(sum);
    lwout[((size_t)bh * NCHUNK + c) * 64 + tid] = sum;
  }
  __syncthreads();

  float am[4][4] = {};
  for (int kk = 0; kk < 64; ++kk) {
    float a[4], bv_[4];
    #pragma unroll
    for (int i = 0; i < 4; ++i) a[i]  = qs[(ty * 4 + i) * 65 + kk];
    #pragma unroll
    for (int j = 0; j < 4; ++j) bv_[j] = ks[(tx * 4 + j) * 65 + kk];
    #pragma unroll
    for (int i = 0; i < 4; ++i)
      #pragma unroll
      for (int j = 0; j < 4; ++j)
        am[i][j] += a[i] * bv_[j];
  }
  __syncthreads();
  float* Am = qs;
  #pragma unroll
  for (int i = 0; i < 4; ++i) {
    const float lwi = lw[ty * 4 + i];
    #pragma unroll
    for (int j = 0; j < 4; ++j)
      Am[(ty * 4 + i) * 65 + tx * 4 + j] = am[i][j] * expf(-fabsf(lwi - lw[tx * 4 + j]));
  }
  __syncthreads();

  const size_t obase = ((size_t)bh * NCHUNK + c) * STW;

  {
    float acc2[4][4] = {};
    for (int uj = 0; uj < 64; ++uj) {
      float a[4], bv_[4];
      #pragma unroll
      for (int i = 0; i < 4; ++i) a[i]  = Am[(ty * 4 + i) * 65 + uj];
      #pragma unroll
      for (int j = 0; j < 4; ++j) bv_[j] = vs[uj * 65 + tx * 4 + j];
      #pragma unroll
      for (int i = 0; i < 4; ++i)
        #pragma unroll
        for (int j = 0; j < 4; ++j)
          acc2[i][j] += a[i] * bv_[j];
    }
    #pragma unroll
    for (int i = 0; i < 4; ++i)
      #pragma unroll
      for (int j = 0; j < 4; ++j)
        intra[obase + (ty * 4 + i) * 65 + tx * 4 + j] = acc2[i][j];
  }
  if (tid < 64) {
    float s = 0.f;
    for (int uj = 0; uj < 64; ++uj) s += Am[tid * 65 + uj];
    intra[obase + tid * 65 + 64] = s;
  }

  {
    float accS[4][4] = {}, accR[4][4] = {};
    for (int u = 0; u < 64; ++u) {
      const float w1 = e1[u], w2 = e2[u];
      float kr[4], vr[4];
      #pragma unroll
      for (int i = 0; i < 4; ++i) kr[i] = ks[u * 65 + ty * 4 + i];
      #pragma unroll
      for (int j = 0; j < 4; ++j) vr[j] = vs[u * 65 + tx * 4 + j];
      #pragma unroll
      for (int i = 0; i < 4; ++i)
        #pragma unroll
        for (int j = 0; j < 4; ++j) {
          const float p = kr[i] * vr[j];
          accS[i][j] += w1 * p;
          accR[i][j] += w2 * p;
        }
    }
    #pragma unroll
    for (int i = 0; i < 4; ++i)
      #pragma unroll
      for (int j = 0; j < 4; ++j) {
        const size_t idx = obase + (ty * 4 + i) * 65 + tx * 4 + j;
        dS[idx] = accS[i][j];
        dR[idx] = accR[i][j];
      }
  }
  if (tid < 64) {
    float sS = 0.f, sR = 0.f;
    for (int u = 0; u < 64; ++u) {
      const float kv_ = ks[u * 65 + tid];
      sS += e1[u] * kv_;
      sR += e2[u] * kv_;
    }
    dS[obase + tid * 65 + 64] = sS;
    dR[obase + tid * 65 + 64] = sR;
  }
}

// ---------------- LION phase B ----------------
__global__ __launch_bounds__(256) void lion_state_kernel(
    float* __restrict__ dS, float* __restrict__ dR,
    const float* __restrict__ lwbuf)
{
  const int bh  = blockIdx.x >> 1;
  const int dir = blockIdx.x & 1;
  const int tid = threadIdx.x;
  float st[17];
  #pragma unroll
  for (int r = 0; r < 17; ++r) st[r] = 0.f;
  if (dir == 0) {
    for (int c = 0; c < NCHUNK; ++c) {
      const float d = expf(lwbuf[((size_t)bh * NCHUNK + c) * 64 + 63]);
      const size_t base = ((size_t)bh * NCHUNK + c) * STW;
      #pragma unroll
      for (int r = 0; r < 17; ++r) {
        const int e = tid + r * 256;
        if (e < STW) {
          const float tmp = dS[base + e];
          dS[base + e] = st[r];
          st[r] = fmaf(d, st[r], tmp);
        }
      }
    }
  } else {
    for (int c = NCHUNK - 1; c >= 0; --c) {
      const float d = expf(lwbuf[((size_t)bh * NCHUNK + c) * 64 + 63]);
      const size_t base = ((size_t)bh * NCHUNK + c) * STW;
      #pragma unroll
      for (int r = 0; r < 17; ++r) {
        const int e = tid + r * 256;
        if (e < STW) {
          const float tmp = dR[base + e];
          dR[base + e] = st[r];
          st[r] = fmaf(d, st[r], tmp);
        }
      }
    }
  }
}

// ---------------- LION phase C ----------------
__global__ __launch_bounds__(256) void lion_cross_kernel(
    const u16* __restrict__ qb, const float* __restrict__ intra,
    const float* __restrict__ Sst, const float* __restrict__ Rst,
    const float* __restrict__ lwbuf, u16* __restrict__ attn)
{
  const int c  = blockIdx.x;
  const int bh = blockIdx.y;
  const int b = bh >> 4, h = bh & 15;
  const int tid = threadIdx.x;
  const int tx = tid & 15, ty = tid >> 4;

  __shared__ float qs[64 * 65];
  __shared__ float Ss[STW];
  __shared__ float Rs[STW];
  __shared__ float lw[64];

  const size_t rowbase = ((size_t)(b * Tq + c * 64)) * Dq + h * 64;
  #pragma unroll
  for (int r = 0; r < 2; ++r) {
    const int s = tid + r * 256;
    const int u = s >> 3, e8 = (s & 7) << 3;
    const uint4 qv = *(const uint4*)(qb + rowbase + (size_t)u * Dq + e8);
    const int o = u * 65 + e8;
    qs[o+0]=bflo(qv.x); qs[o+1]=bfhi(qv.x); qs[o+2]=bflo(qv.y); qs[o+3]=bfhi(qv.y);
    qs[o+4]=bflo(qv.z); qs[o+5]=bfhi(qv.z); qs[o+6]=bflo(qv.w); qs[o+7]=bfhi(qv.w);
  }
  const size_t obase = ((size_t)bh * NCHUNK + c) * STW;
  for (int e = tid; e < STW; e += 256) {
    Ss[e] = Sst[obase + e];
    Rs[e] = Rst[obase + e];
  }
  if (tid < 64) lw[tid] = lwbuf[((size_t)bh * NCHUNK + c) * 64 + tid];
  __syncthreads();
  const float lwE = lw[63];

  float aS[4][4] = {}, aR[4][4] = {};
  for (int kk = 0; kk < 64; ++kk) {
    float a[4], s4[4], r4[4];
    #pragma unroll
    for (int i = 0; i < 4; ++i) a[i]  = qs[(ty * 4 + i) * 65 + kk];
    #pragma unroll
    for (int j = 0; j < 4; ++j) { s4[j] = Ss[kk * 65 + tx * 4 + j]; r4[j] = Rs[kk * 65 + tx * 4 + j]; }
    #pragma unroll
    for (int i = 0; i < 4; ++i)
      #pragma unroll
      for (int j = 0; j < 4; ++j) {
        aS[i][j] += a[i] * s4[j];
        aR[i][j] += a[i] * r4[j];
      }
  }
  float dnS = 0.f, dnR = 0.f;
  if (tid < 64) {
    for (int kk = 0; kk < 64; ++kk) {
      const float qv = qs[tid * 65 + kk];
      dnS += qv * Ss[kk * 65 + 64];
      dnR += qv * Rs[kk * 65 + 64];
    }
  }
  __syncthreads();
  float* outb = qs;
  #pragma unroll
  for (int i = 0; i < 4; ++i) {
    const float ef = expf(lw[ty * 4 + i]);
    const float eb = expf(lwE - lw[ty * 4 + i]);
    #pragma unroll
    for (int j = 0; j < 4; ++j) {
      const int idx = (ty * 4 + i) * 65 + tx * 4 + j;
      outb[idx] = intra[obase + idx] + ef * aS[i][j] + eb * aR[i][j];
    }
  }
  if (tid < 64) {
    outb[tid * 65 + 64] = intra[obase + tid * 65 + 64]
                        + expf(lw[tid]) * dnS + expf(lwE - lw[tid]) * dnR;
  }
  __syncthreads();
  for (int e = tid; e < 4096; e += 256) {
    const int ui = e >> 6, kk = e & 63;
    const float den = fmaxf(outb[ui * 65 + 64], 1e-6f);
    attn[rowbase + (size_t)ui * Dq + kk] = f2bf(outb[ui * 65 + kk] / den);
  }
}

// ---------------- launch ----------------
extern "C" void kernel_launch(void* const* d_in, const int* in_sizes, int n_in,
                              void* d_out, int out_size, void* d_ws, size_t ws_size,
                              hipStream_t stream)
{
  const float* x     = (const float*)d_in[0];
  const float* q_w   = (const float*)d_in[1];
  const float* q_b   = (const float*)d_in[2];
  const float* k_w   = (const float*)d_in[3];
  const float* k_b   = (const float*)d_in[4];
  const float* v_w   = (const float*)d_in[5];
  const float* v_b   = (const float*)d_in[6];
  const float* o_w   = (const float*)d_in[7];
  const float* o_b   = (const float*)d_in[8];
  const float* ln1_w = (const float*)d_in[9];
  const float* ln1_b = (const float*)d_in[10];
  const float* ln2_w = (const float*)d_in[11];
  const float* ln2_b = (const float*)d_in[12];
  const float* dec_w = (const float*)d_in[13];
  const float* dec_b = (const float*)d_in[14];
  const float* f1_w  = (const float*)d_in[15];
  const float* f1_b  = (const float*)d_in[16];
  const float* f2_w  = (const float*)d_in[17];
  const float* f2_b  = (const float*)d_in[18];
  float* out = (float*)d_out;
  float* ws  = (float*)d_ws;

  size_t o = 0;
  float* xn    = ws + o; o += (size_t)ROWS * Dq;        // fp32 LN1 out (declam)
  float* xa    = ws + o; o += (size_t)ROWS * Dq;        // fp32 post-attn residual
  u16*   xnb   = (u16*)(ws + o); o += (size_t)ROWS * Dq / 2;
  u16*   qbuf  = (u16*)(ws + o); o += (size_t)ROWS * Dq / 2;
  u16*   kbuf  = (u16*)(ws + o); o += (size_t)ROWS * Dq / 2;
  u16*   vbuf  = (u16*)(ws + o); o += (size_t)ROWS * Dq / 2;
  u16*   attnb = (u16*)(ws + o); o += (size_t)ROWS * Dq / 2;
  u16*   hb    = qbuf;  // FFN hidden 4096x4096 bf16 = 32 MB aliases qbuf..attnb (dead then)
  float* llam  = ws + o; o += (size_t)ROWS * Hq;
  float* lwb   = ws + o; o += (size_t)32 * NCHUNK * 64;
  float* dSb   = ws + o; o += (size_t)32 * NCHUNK * STW;
  float* dRb   = ws + o; o += (size_t)32 * NCHUNK * STW;
  float* intrab= ws + o; o += (size_t)32 * NCHUNK * STW;
  u16*   x2b   = (u16*)intrab;  // LN2 out aliases intrab (dead after lion_cross)
  u16*   qkvT  = (u16*)(ws + o); o += (size_t)3 * Dq * Dq / 2;  // [3072][1024] concat
  u16*   owT   = (u16*)(ws + o); o += (size_t)Dq * Dq / 2;
  u16*   f1T   = (u16*)(ws + o); o += (size_t)Dq * FFNq / 2;
  u16*   f2T   = (u16*)(ws + o); o += (size_t)Dq * FFNq / 2;

  // weight bf16 transpose (qkv concatenated along N)
  wconv<<<dim3(16, 16), 256, 0, stream>>>(q_w, qkvT,                 Dq, Dq);
  wconv<<<dim3(16, 16), 256, 0, stream>>>(k_w, qkvT + 1024 * 1024,   Dq, Dq);
  wconv<<<dim3(16, 16), 256, 0, stream>>>(v_w, qkvT + 2 * 1024 * 1024, Dq, Dq);
  wconv<<<dim3(16, 16), 256, 0, stream>>>(o_w, owT, Dq, Dq);
  wconv<<<dim3(64, 16), 256, 0, stream>>>(f1_w, f1T, Dq, FFNq);
  wconv<<<dim3(16, 64), 256, 0, stream>>>(f2_w, f2T, FFNq, Dq);

  ln_kernel<true><<<ROWS, 256, 0, stream>>>(x, ln1_w, ln1_b, xn, xnb);
  mgemm_qkv<<<dim3(24, 32), 256, 0, stream>>>(xnb, qkvT, q_b, k_b, v_b, qbuf, kbuf, vbuf);
  declam_kernel<<<ROWS, 256, 0, stream>>>(xn, dec_w, dec_b, llam);

  lion_chunk_kernel<<<dim3(NCHUNK, 32), 256, 0, stream>>>(qbuf, kbuf, vbuf, llam, intrab, dSb, dRb, lwb);
  lion_state_kernel<<<64, 256, 0, stream>>>(dSb, dRb, lwb);
  lion_cross_kernel<<<dim3(NCHUNK, 32), 256, 0, stream>>>(qbuf, intrab, dSb, dRb, lwb, attnb);

  mgemm<ACT_NONE, true, true><<<dim3(8, 32), 256, 0, stream>>>(attnb, owT, o_b, x, xa, ROWS, Dq, Dq);
  ln_kernel<false><<<ROWS, 256, 0, stream>>>(xa, ln2_w, ln2_b, nullptr, x2b);
  mgemm<ACT_GELU, false, false><<<dim3(32, 32), 256, 0, stream>>>(x2b, f1T, f1_b, nullptr, hb, ROWS, FFNq, Dq);
  mgemm<ACT_NONE, true, true><<<dim3(8, 32), 256, 0, stream>>>(hb, f2T, f2_b, xa, out, ROWS, Dq, FFNq);
}